// Round 4
// baseline (78.916 us; speedup 1.0000x reference)
//
#include <hip/hip_runtime.h>

// LIF integrate-fire-reset over the time axis.
// x: [B=64, C=2048, T=256] f32 row-major -> 131072 rows of 256 contiguous floats.
// u_t = TAU*u_{t-1}*(1-s_{t-1}) + x_t ; s_t = (u_t > VTH).
//
// R2 structure (measured best: 44.8us, 1x write traffic, 0 bank conflicts):
//   256-thread blocks, 512 blocks (2 blocks/CU, 8 waves/CU),
//   coalesced float4 loads staged to double-buffered LDS (stride 36 words/row:
//   conflict-free b128 writes AND reads), lgkmcnt-only s_barrier per chunk
//   (never drains vmcnt), spike masks exchanged via wave shuffle, nontemporal
//   coalesced float4 stores.
// R4 change: register prefetch DEPTH 2 -- chunk k+2's global loads are issued
//   during chunk k, so the staging ds_write never waits on HBM-miss latency
//   (~900 cyc); load->use slack is > 1.5 chunk periods.

#define T_LEN 256
#define TQ 64              // float4 per row
#define NCH 8              // 8 chunks of 32 timesteps
#define RPB 256            // rows per block == threads per block
#define XS_STRIDE 36       // LDS words per row (32 + 4 pad)

#define TAU 0.25f
#define VTH 0.5f

typedef float f32x4 __attribute__((ext_vector_type(4)));

__global__ __launch_bounds__(RPB, 2)
void lif_kernel(const float* __restrict__ x, float* __restrict__ out) {
    __shared__ __align__(16) float xs[2][RPB * XS_STRIDE];  // 2 x 36864 B

    const int tid  = threadIdx.x;
    const int lane = tid & 63;
    const int wv   = tid >> 6;
    const long rbase = (long)blockIdx.x * RPB;

    const float4* __restrict__ x4 = reinterpret_cast<const float4*>(x);

    const int qs = tid & 7;   // float4 slot this thread stages
    const int rs = tid >> 3;  // base staging row (stride 32 per i)

    // ---- prologue: prefetch chunks 0 and 1 into registers (depth 2) ----
    float4 p[2][8];
    #pragma unroll
    for (int i = 0; i < 8; ++i)
        p[0][i] = x4[(rbase + rs + i * 32) * TQ + 0 * 8 + qs];
    #pragma unroll
    for (int i = 0; i < 8; ++i)
        p[1][i] = x4[(rbase + rs + i * 32) * TQ + 1 * 8 + qs];

    float u = 0.0f;
    bool sprev = false;

    #pragma unroll
    for (int k = 0; k < NCH; ++k) {
        float* buf = xs[k & 1];

        // ---- stage chunk k: regs -> LDS (b128, conflict-free) ----
        #pragma unroll
        for (int i = 0; i < 8; ++i)
            *reinterpret_cast<float4*>(&buf[(rs + i * 32) * XS_STRIDE + 4 * qs]) = p[k & 1][i];

        // lgkm-only barrier: do NOT drain vmcnt (prefetch loads + stores stay in flight)
        asm volatile("s_waitcnt lgkmcnt(0)" ::: "memory");
        __builtin_amdgcn_s_barrier();

        // ---- prefetch chunk k+2 into the register slot just freed ----
        if (k + 2 < NCH) {
            #pragma unroll
            for (int i = 0; i < 8; ++i)
                p[k & 1][i] = x4[(rbase + rs + i * 32) * TQ + (k + 2) * 8 + qs];
        }

        // ---- read own row from LDS ----
        float4 v[8];
        #pragma unroll
        for (int i = 0; i < 8; ++i)
            v[i] = *reinterpret_cast<const float4*>(&buf[tid * XS_STRIDE + 4 * i]);

        // ---- 32 sequential LIF steps, bit-exact vs reference ----
        unsigned int m = 0;
        #pragma unroll
        for (int i = 0; i < 8; ++i) {
            float e[4] = { v[i].x, v[i].y, v[i].z, v[i].w };
            #pragma unroll
            for (int j = 0; j < 4; ++j) {
                float um = sprev ? 0.0f : __fmul_rn(TAU, u);
                u = __fadd_rn(um, e[j]);
                sprev = u > VTH;
                m |= (sprev ? 1u : 0u) << (i * 4 + j);
            }
        }

        // ---- wave-local mask exchange + nontemporal coalesced stores ----
        #pragma unroll
        for (int i = 0; i < 8; ++i) {
            int rowl = i * 8 + (lane >> 3);                      // row within wave tile
            unsigned int mr = (unsigned int)__shfl((int)m, rowl, 64);
            int toff = 4 * (lane & 7);
            f32x4 o;
            o[0] = ((mr >> (toff + 0)) & 1u) ? 1.0f : 0.0f;
            o[1] = ((mr >> (toff + 1)) & 1u) ? 1.0f : 0.0f;
            o[2] = ((mr >> (toff + 2)) & 1u) ? 1.0f : 0.0f;
            o[3] = ((mr >> (toff + 3)) & 1u) ? 1.0f : 0.0f;
            long gq = (rbase + wv * 64 + rowl) * (long)TQ + k * 8 + (lane & 7);
            __builtin_nontemporal_store(o, reinterpret_cast<f32x4*>(out) + gq);
        }
        // Double-buffered LDS: next iteration writes the other buffer, so no
        // second barrier is needed (this buffer's reads finished before our own
        // compute; the k+1 stage targets the other buffer).
    }
}

extern "C" void kernel_launch(void* const* d_in, const int* in_sizes, int n_in,
                              void* d_out, int out_size, void* d_ws, size_t ws_size,
                              hipStream_t stream) {
    const float* x = (const float*)d_in[0];
    float* out = (float*)d_out;
    const int total = in_sizes[0];      // 64*2048*256
    const int nrows = total / T_LEN;    // 131072
    const int blocks = nrows / RPB;     // 512
    lif_kernel<<<blocks, RPB, 0, stream>>>(x, out);
}